// Round 10
// baseline (39452.100 us; speedup 1.0000x reference)
//
#include <hip/hip_runtime.h>

// ESN recurrence on MI355X — R14: R13 + producer consolidation 16 -> 4.
// T=4096 steps, B=64, I=128, H=1024. out = h_T [64,1024] fp32.
//
// 16 blocks x 1024 threads (16 waves). Block (m, q): batch rows m*16..+15,
// cols q*256..+255 (16 n-groups, one per wave — per-wave compute code is
// R13-verbatim). The per-step all-to-all inside an m-group narrows from 16
// producers to 4: poll 4 flags (was 16), straggler max over 4 (was 16),
// exchange reads 4x less (2.1GB -> 0.5GB issued), publish 4 flags.
// Protocol is R13-verbatim: wave-0 poll + ballot, barriers, atomicExch
// publish at LLC coherence point, ack(vmcnt 0) -> barrier -> flag atomic,
// 128B-padded flags, double-buffered h, transposed conflict-free h_lds,
// acc[4] chains, fp16 everywhere.

#define TT 4096
#define BB 64
#define II 128
#define HH 1024

typedef _Float16 f16x8 __attribute__((ext_vector_type(8)));
typedef float f32x4 __attribute__((ext_vector_type(4)));
typedef unsigned int u32x4 __attribute__((ext_vector_type(4)));

static __device__ __forceinline__ unsigned short f2h_bits(float f) {
    _Float16 h = (_Float16)f;          // v_cvt_f16_f32 (RNE)
    return __builtin_bit_cast(unsigned short, h);
}

static __device__ __forceinline__ u32x4 gload16_sc1(const unsigned int* p) {
    u32x4 r;
    asm volatile("global_load_dwordx4 %0, %1, off sc1"
                 : "=v"(r) : "v"(p) : "memory");
    return r;
}

__global__ __launch_bounds__(1024, 1) void esn_kernel(
    const float* __restrict__ x, const float* __restrict__ wih,
    const float* __restrict__ whh, const float* __restrict__ bih,
    const float* __restrict__ bhh, float* __restrict__ out,
    unsigned int* __restrict__ hbu0, unsigned int* __restrict__ hbu1,
    unsigned int* __restrict__ flags)
{
    __shared__ __align__(16) unsigned short h_lds[128 * 16 * 8]; // 32 KB [k16][row]
    __shared__ __align__(16) unsigned short x_lds[16 * 136];     // 4.25 KB
    __shared__ __align__(16) unsigned int   c_lds[16 * 132];     // 8.25 KB

    const int tid  = threadIdx.x;
    const int lane = tid & 63;
    const int wv   = tid >> 6;      // 0..15
    const int col  = lane & 15;     // MFMA col (n) / A row (m)
    const int quad = lane >> 4;

    const int blk    = blockIdx.x;          // 0..15
    const int m      = blk >> 2;            // batch group 0..3
    const int m_base = m * 16;
    const int q      = blk & 3;             // producer index within group 0..3
    const int n_idx  = q * 16 + wv;         // 0..63
    const int n_base = n_idx * 16;

    // ---- one-time: weights into registers as fp16 (R13-verbatim) ----
    f16x8 wh[32], wi[4];
#pragma unroll
    for (int kt = 0; kt < 32; ++kt) {
        const float* p = whh + (size_t)(n_base + col) * HH + kt * 32 + quad * 8;
        f16x8 w;
#pragma unroll
        for (int j = 0; j < 8; ++j) w[j] = (_Float16)p[j];
        wh[kt] = w;
    }
#pragma unroll
    for (int kt = 0; kt < 4; ++kt) {
        const float* p = wih + (size_t)(n_base + col) * II + kt * 32 + quad * 8;
        f16x8 w;
#pragma unroll
        for (int j = 0; j < 8; ++j) w[j] = (_Float16)p[j];
        wi[kt] = w;
    }
    const float bias_sum = bih[n_base + col] + bhh[n_base + col];

    // h staging (1024 threads, 16 chunks): chunk csrc, row crow, part 0..3
    const int csrc = tid >> 6;        // chunk 0..15 (uniform per wave)
    const int crow = (tid >> 2) & 15; // row within chunk
    const int part = tid & 3;         // 8-dword slice within row
    // x staging (first 256 threads only, R13-verbatim mapping)
    const int sr = (tid >> 4) & 15;
    const int sc = tid & 15;
    // flags: one per (group, producer q), padded 128B (32 dwords)
    const unsigned int* fl = flags + m * 128;   // + lane*32 in the poll

    // x software pipeline: prefetch x_0 (threads 0..255 only)
    f32x4 xa, xb;
    if (tid < 256) {
        const float* gp = x + (size_t)(m_base + sr) * II + sc * 8;
        xa = *(const f32x4*)gp;
        xb = *(const f32x4*)(gp + 4);
    }

    for (int t = 0; t < TT; ++t) {
        const unsigned int* rbu = (t & 1) ? hbu1 : hbu0;
        unsigned int*       wbu = (t & 1) ? hbu0 : hbu1;

        // (1) convert prefetched x_t -> fp16 -> x_lds (threads 0..255)
        if (tid < 256) {
            f16x8 v;
#pragma unroll
            for (int j = 0; j < 4; ++j) v[j] = (_Float16)xa[j];
#pragma unroll
            for (int j = 0; j < 4; ++j) v[4 + j] = (_Float16)xb[j];
            *(f16x8*)(x_lds + sr * 136 + sc * 8) = v;
        }

        // (2) wait until all 4 producers in this m-group published h^t
        //     (t=0: flags zeroed, v>=0 passes; hbu0 zeroed = h0)
        if (wv == 0) {
            const bool skip = (lane >= 4);
            const unsigned int* fp = fl + lane * 32;
            for (;;) {
                unsigned int v = 0;
                if (!skip)
                    asm volatile("global_load_dword %0, %1, off sc1\n\t"
                                 "s_waitcnt vmcnt(0)"
                                 : "=v"(v) : "v"(fp) : "memory");
                if (__ballot(skip || v >= (unsigned int)t) == ~0ull) break;
            }
        }
        __syncthreads();

        // (3) stage h^t: 16 chunks x 2KB over 1024 threads (8 dwords each,
        //     perfectly coalesced: wave covers one contiguous 2KB chunk) ->
        //     transposed LDS [k16][row] (bank-balanced, R13 layout)
        {
            const unsigned int* gp = rbu + (size_t)(m * 16 + csrc) * 512
                                     + crow * 32 + part * 8;
            u32x4 a0 = gload16_sc1(gp);
            u32x4 a1 = gload16_sc1(gp + 4);
            asm volatile("s_waitcnt vmcnt(0)"
                         : "+v"(a0), "+v"(a1) :: "memory");
            unsigned short* lp = h_lds + crow * 8;
            *(u32x4*)(lp + (csrc * 8 + part * 2 + 0) * 128) = a0;
            *(u32x4*)(lp + (csrc * 8 + part * 2 + 1) * 128) = a1;
        }
        __syncthreads();

        // (4) prefetch x_{t+1} (threads 0..255; fills during MFMA+epilogue)
        if (tid < 256 && t + 1 < TT) {
            const float* gp = x + (size_t)(t + 1) * (BB * II)
                              + (size_t)(m_base + sr) * II + sc * 8;
            xa = *(const f32x4*)gp;
            xb = *(const f32x4*)(gp + 4);
        }

        // (5) MFMAs: 32 h + 4 x, fp16, 4 accumulator chains (R13-verbatim)
        f32x4 acc[4];
#pragma unroll
        for (int i = 0; i < 4; ++i) acc[i] = (f32x4){0.f, 0.f, 0.f, 0.f};
#pragma unroll
        for (int kt = 0; kt < 32; ++kt) {
            f16x8 a = *(const f16x8*)(h_lds + (4 * kt + quad) * 128 + col * 8);
            acc[kt & 3] = __builtin_amdgcn_mfma_f32_16x16x32_f16(
                a, wh[kt], acc[kt & 3], 0, 0, 0);
        }
        const unsigned short* xrow = x_lds + col * 136;
#pragma unroll
        for (int kt = 0; kt < 4; ++kt) {
            f16x8 a = *(const f16x8*)(xrow + kt * 32 + quad * 8);
            acc[kt & 3] = __builtin_amdgcn_mfma_f32_16x16x32_f16(
                a, wi[kt], acc[kt & 3], 0, 0, 0);
        }

        // (6) epilogue: bias + tanh; pack fp16 pairs -> c_lds [16][132]
        float th[4];
#pragma unroll
        for (int i = 0; i < 4; ++i) {
            float pre = (acc[0][i] + acc[1][i]) + (acc[2][i] + acc[3][i])
                        + bias_sum;
            float pc  = fminf(fmaxf(pre, -9.f), 9.f);
            float e   = __expf(2.f * pc);
            th[i] = (e - 1.f) / (e + 1.f);
        }
        {
            unsigned int p01 = (unsigned int)f2h_bits(th[0]) |
                               ((unsigned int)f2h_bits(th[1]) << 16);
            unsigned int p23 = (unsigned int)f2h_bits(th[2]) |
                               ((unsigned int)f2h_bits(th[3]) << 16);
            unsigned int q01 = (unsigned int)__shfl_xor((int)p01, 1, 64);
            unsigned int q23 = (unsigned int)__shfl_xor((int)p23, 1, 64);
            if (!(lane & 1)) {
                unsigned int w0 = (p01 & 0xFFFFu) | (q01 << 16);
                unsigned int w1 = (p01 >> 16) | (q01 & 0xFFFF0000u);
                unsigned int w2 = (p23 & 0xFFFFu) | (q23 << 16);
                unsigned int w3 = (p23 >> 16) | (q23 & 0xFFFF0000u);
                // within-block chunk wv>>2, col group wv&3, col pair col>>1
                const int cc = (wv >> 2) * 32 + (wv & 3) * 8 + (col >> 1);
                unsigned int* cl = c_lds + (quad * 4) * 132 + cc;
                cl[0]       = w0;
                cl[132]     = w1;
                cl[2 * 132] = w2;
                cl[3 * 132] = w3;
            }
        }
        if (t == TT - 1) {
#pragma unroll
            for (int i = 0; i < 4; ++i)
                out[(size_t)(m_base + quad * 4 + i) * HH + n_base + col] = th[i];
        }
        __syncthreads();

        // (7) publish 4 chunks (8KB) via atomicExch (R13-verbatim ordering:
        //     atomics -> ack -> barrier -> padded flag atomic)
        if (t < TT - 1) {
            const int ch = tid >> 8;          // 0..3 within-block chunk
            const int rt = (tid >> 4) & 15;   // row
            const int c0 = (tid & 15) * 2;    // 0,2,..,30
            unsigned int* dst = wbu + (size_t)(m * 16 + q * 4 + ch) * 512
                                + rt * 32 + c0;
            atomicExch(dst,     c_lds[rt * 132 + ch * 32 + c0]);
            atomicExch(dst + 1, c_lds[rt * 132 + ch * 32 + c0 + 1]);
            asm volatile("s_waitcnt vmcnt(0)" ::: "memory");
            __syncthreads();
            if (tid == 0)
                atomicExch((unsigned int*)(flags + (m * 4 + q) * 32),
                           (unsigned int)(t + 1));
        }
    }
}

extern "C" void kernel_launch(void* const* d_in, const int* in_sizes, int n_in,
                              void* d_out, int out_size, void* d_ws, size_t ws_size,
                              hipStream_t stream) {
    const float* x   = (const float*)d_in[0];
    const float* wih = (const float*)d_in[1];
    const float* whh = (const float*)d_in[2];
    const float* bih = (const float*)d_in[3];
    const float* bhh = (const float*)d_in[4];
    float* out = (float*)d_out;

    unsigned int* hbu0  = (unsigned int*)d_ws;                      // 128 KB
    unsigned int* hbu1  = hbu0 + 32768;                             // 128 KB
    unsigned int* flags = (unsigned int*)((char*)d_ws + 262144);    // 2 KB
    // flag slot: (m*4 + producer) * 32 dwords (128B padding per flag)

    // zero h buffers (h0 = 0) + padded flags (ws is poisoned 0xAA)
    hipMemsetAsync(d_ws, 0, 262144 + 2048, stream);

    esn_kernel<<<dim3(16), dim3(1024), 0, stream>>>(x, wih, whh, bih, bhh,
                                                    out, hbu0, hbu1, flags);
}

// Round 11
// 14090.305 us; speedup vs baseline: 2.7999x; 2.7999x over previous
//
#include <hip/hip_runtime.h>

// ESN recurrence on MI355X — R15: R13 + tagged fire-and-forget publish
// (ack RT removed). T=4096 steps, B=64, I=128, H=1024. out = h_T fp32.
//
// Base: R13 (15.45 ms, passed; 64 blocks x 256 threads, transposed
// conflict-free h_lds, acc[4], fp16, atomicExch publish, padded flags).
// Diffs (exchange only; every mechanism HW-proven in R5/R10/R13):
//  1. Published words carry a generation tag in bit30 (= bit14 of the odd
//     fp16, provably 0 for |tanh|<1). Generations 1,1,0,0,... over steps;
//     zero-init = tag 0 (R5/R10 formulas verbatim).
//  2. Publish: ONE 64-bit atomicExch per thread (256 u64 ops, was 512 u32),
//     then raw s_barrier -> flag atomic. NO vmcnt ack, no extra barrier:
//     data-before-flag ordering is enforced by the consumer tag check.
//  3. Consumer stage: tag-check 16 dwords (one per 8B atomic unit) in the
//     staged registers; per-thread bounded retry (reload own 128B row);
//     clear tag bits; write h_lds. Exhausted retry poisons final out.
// R14 lesson encoded: 256-thread blocks only (1024-thr block capped VGPR
// at 64 -> weight spill -> 39 ms).

#define TT 4096
#define BB 64
#define II 128
#define HH 1024
#define TAGBIT 0x40000000u

typedef _Float16 f16x8 __attribute__((ext_vector_type(8)));
typedef float f32x4 __attribute__((ext_vector_type(4)));
typedef unsigned int u32x4 __attribute__((ext_vector_type(4)));

static __device__ __forceinline__ unsigned short f2h_bits(float f) {
    _Float16 h = (_Float16)f;          // v_cvt_f16_f32 (RNE)
    return __builtin_bit_cast(unsigned short, h);
}

static __device__ __forceinline__ u32x4 gload16_sc1(const unsigned int* p) {
    u32x4 r;
    asm volatile("global_load_dwordx4 %0, %1, off sc1"
                 : "=v"(r) : "v"(p) : "memory");
    return r;
}

__global__ __launch_bounds__(256, 1) void esn_kernel(
    const float* __restrict__ x, const float* __restrict__ wih,
    const float* __restrict__ whh, const float* __restrict__ bih,
    const float* __restrict__ bhh, float* __restrict__ out,
    unsigned int* __restrict__ hbu0, unsigned int* __restrict__ hbu1,
    unsigned int* __restrict__ flags)
{
    __shared__ __align__(16) unsigned short h_lds[128 * 16 * 8]; // 32 KB [k16][row]
    __shared__ __align__(16) unsigned short x_lds[16 * 136];     // 4.25 KB
    __shared__ __align__(16) unsigned int   c_lds[16 * 36];      // 2.25 KB

    const int tid  = threadIdx.x;
    const int lane = tid & 63;
    const int wv   = tid >> 6;
    const int col  = lane & 15;     // MFMA col (n) / A row (m)
    const int quad = lane >> 4;

    const int blk    = blockIdx.x;
    const int m      = blk >> 4;            // batch group 0..3
    const int m_base = m * 16;
    const int jj     = blk & 15;            // producer index within group
    const int n_idx  = jj * 4 + wv;
    const int n_base = n_idx * 16;

    // ---- one-time: weights into registers as fp16 (R13-verbatim) ----
    f16x8 wh[32], wi[4];
#pragma unroll
    for (int kt = 0; kt < 32; ++kt) {
        const float* p = whh + (size_t)(n_base + col) * HH + kt * 32 + quad * 8;
        f16x8 w;
#pragma unroll
        for (int j = 0; j < 8; ++j) w[j] = (_Float16)p[j];
        wh[kt] = w;
    }
#pragma unroll
    for (int kt = 0; kt < 4; ++kt) {
        const float* p = wih + (size_t)(n_base + col) * II + kt * 32 + quad * 8;
        f16x8 w;
#pragma unroll
        for (int j = 0; j < 8; ++j) w[j] = (_Float16)p[j];
        wi[kt] = w;
    }
    const float bias_sum = bih[n_base + col] + bhh[n_base + col];

    const int sr   = tid >> 4;        // x-staging row 0..15
    const int sc   = tid & 15;        // x-staging col group 0..15
    const int csrc = tid >> 4;        // h chunk this thread stages 0..15
    const int crow = tid & 15;        // row within that chunk
    // flags: one per (group, producer), padded 128B (32 dwords) apart
    const unsigned int* fl = flags + m * 512;   // + lane*32 in the poll

    // x software pipeline: prefetch x_0 into registers (R13-verbatim)
    f32x4 xa, xb;
    {
        const float* gp = x + (size_t)(m_base + sr) * II + sc * 8;
        xa = *(const f32x4*)gp;
        xb = *(const f32x4*)(gp + 4);
    }

    unsigned int fail = 0;
    for (int t = 0; t < TT; ++t) {
        const unsigned int* rbu = (t & 1) ? hbu1 : hbu0;
        unsigned int*       wbu = (t & 1) ? hbu0 : hbu1;
        // tag generations (R5/R10-verbatim): producer at step s tags
        // g(s)=1^((s>>1)&1); consumer at t expects g(t-1); zero-init = 0.
        const unsigned int etag =
            (t == 0) ? 0u : ((1u ^ (((unsigned)(t - 1) >> 1) & 1u)) << 30);
        const unsigned int my_tag = (1u ^ (((unsigned)t >> 1) & 1u)) << 30;

        // (1) convert prefetched x_t -> fp16 -> x_lds (R13-verbatim)
        {
            f16x8 v;
#pragma unroll
            for (int j = 0; j < 4; ++j) v[j] = (_Float16)xa[j];
#pragma unroll
            for (int j = 0; j < 4; ++j) v[4 + j] = (_Float16)xb[j];
            *(f16x8*)(x_lds + sr * 136 + sc * 8) = v;
        }

        // (2) wait until every producer in this m-group has published h^t
        //     (t=0: flags zeroed, v>=0 passes)  [R13-verbatim poll]
        if (wv == 0) {
            const bool skip = (lane >= 16);
            const unsigned int* fp = fl + lane * 32;
            for (;;) {
                unsigned int v = 0;
                if (!skip)
                    asm volatile("global_load_dword %0, %1, off sc1\n\t"
                                 "s_waitcnt vmcnt(0)"
                                 : "=v"(v) : "v"(fp) : "memory");
                if (__ballot(skip || v >= (unsigned int)t) == ~0ull) break;
            }
        }
        __syncthreads();

        // (3) stage h^t -> tag-verify in regs -> transposed LDS [k16][row]
        {
            const unsigned int* gp = rbu + (size_t)(m * 16 + csrc) * 512 + crow * 32;
            u32x4 a0 = gload16_sc1(gp);
            u32x4 a1 = gload16_sc1(gp + 4);
            u32x4 a2 = gload16_sc1(gp + 8);
            u32x4 a3 = gload16_sc1(gp + 12);
            u32x4 a4 = gload16_sc1(gp + 16);
            u32x4 a5 = gload16_sc1(gp + 20);
            u32x4 a6 = gload16_sc1(gp + 24);
            u32x4 a7 = gload16_sc1(gp + 28);
            int rounds = 0;
            for (;;) {
                asm volatile("s_waitcnt vmcnt(0)"
                             : "+v"(a0), "+v"(a1), "+v"(a2), "+v"(a3),
                               "+v"(a4), "+v"(a5), "+v"(a6), "+v"(a7)
                             :: "memory");
                // one check per 8B atomic unit (dwords 0 and 2 of each x4)
                unsigned int bad =
                    (a0[0] ^ etag) | (a0[2] ^ etag) | (a1[0] ^ etag) | (a1[2] ^ etag) |
                    (a2[0] ^ etag) | (a2[2] ^ etag) | (a3[0] ^ etag) | (a3[2] ^ etag) |
                    (a4[0] ^ etag) | (a4[2] ^ etag) | (a5[0] ^ etag) | (a5[2] ^ etag) |
                    (a6[0] ^ etag) | (a6[2] ^ etag) | (a7[0] ^ etag) | (a7[2] ^ etag);
                if (!(bad & TAGBIT)) break;               // all fresh
                if (++rounds > 65536) { fail = 1u; break; }
                a0 = gload16_sc1(gp);
                a1 = gload16_sc1(gp + 4);
                a2 = gload16_sc1(gp + 8);
                a3 = gload16_sc1(gp + 12);
                a4 = gload16_sc1(gp + 16);
                a5 = gload16_sc1(gp + 20);
                a6 = gload16_sc1(gp + 24);
                a7 = gload16_sc1(gp + 28);
            }
            const unsigned int clr = ~TAGBIT;
            a0 &= clr; a1 &= clr; a2 &= clr; a3 &= clr;
            a4 &= clr; a5 &= clr; a6 &= clr; a7 &= clr;
            unsigned short* lp = h_lds + crow * 8;
            *(u32x4*)(lp + (csrc * 8 + 0) * 128) = a0;
            *(u32x4*)(lp + (csrc * 8 + 1) * 128) = a1;
            *(u32x4*)(lp + (csrc * 8 + 2) * 128) = a2;
            *(u32x4*)(lp + (csrc * 8 + 3) * 128) = a3;
            *(u32x4*)(lp + (csrc * 8 + 4) * 128) = a4;
            *(u32x4*)(lp + (csrc * 8 + 5) * 128) = a5;
            *(u32x4*)(lp + (csrc * 8 + 6) * 128) = a6;
            *(u32x4*)(lp + (csrc * 8 + 7) * 128) = a7;
        }
        __syncthreads();

        // (4) prefetch x_{t+1} (fills during MFMA + epilogue) [R13-verbatim]
        if (t + 1 < TT) {
            const float* gp = x + (size_t)(t + 1) * (BB * II)
                              + (size_t)(m_base + sr) * II + sc * 8;
            xa = *(const f32x4*)gp;
            xb = *(const f32x4*)(gp + 4);
        }

        // (5) MFMAs: 32 h + 4 x, fp16, 4 accumulator chains (R13-verbatim)
        f32x4 acc[4];
#pragma unroll
        for (int i = 0; i < 4; ++i) acc[i] = (f32x4){0.f, 0.f, 0.f, 0.f};
#pragma unroll
        for (int kt = 0; kt < 32; ++kt) {
            f16x8 a = *(const f16x8*)(h_lds + (4 * kt + quad) * 128 + col * 8);
            acc[kt & 3] = __builtin_amdgcn_mfma_f32_16x16x32_f16(
                a, wh[kt], acc[kt & 3], 0, 0, 0);
        }
        const unsigned short* xrow = x_lds + col * 136;
#pragma unroll
        for (int kt = 0; kt < 4; ++kt) {
            f16x8 a = *(const f16x8*)(xrow + kt * 32 + quad * 8);
            acc[kt & 3] = __builtin_amdgcn_mfma_f32_16x16x32_f16(
                a, wi[kt], acc[kt & 3], 0, 0, 0);
        }

        // (6) epilogue: bias + tanh; pack TAGGED fp16 pairs -> c_lds [16][36]
        float th[4];
#pragma unroll
        for (int i = 0; i < 4; ++i) {
            float pre = (acc[0][i] + acc[1][i]) + (acc[2][i] + acc[3][i])
                        + bias_sum;
            float pc  = fminf(fmaxf(pre, -9.f), 9.f);
            float e   = __expf(2.f * pc);
            th[i] = (e - 1.f) / (e + 1.f);
        }
        {
            unsigned int p01 = (unsigned int)f2h_bits(th[0]) |
                               ((unsigned int)f2h_bits(th[1]) << 16);
            unsigned int p23 = (unsigned int)f2h_bits(th[2]) |
                               ((unsigned int)f2h_bits(th[3]) << 16);
            unsigned int q01 = (unsigned int)__shfl_xor((int)p01, 1, 64);
            unsigned int q23 = (unsigned int)__shfl_xor((int)p23, 1, 64);
            if (!(lane & 1)) {
                unsigned int w0 = ((p01 & 0xFFFFu) | (q01 << 16)) | my_tag;
                unsigned int w1 = ((p01 >> 16) | (q01 & 0xFFFF0000u)) | my_tag;
                unsigned int w2 = ((p23 & 0xFFFFu) | (q23 << 16)) | my_tag;
                unsigned int w3 = ((p23 >> 16) | (q23 & 0xFFFF0000u)) | my_tag;
                const int c = wv * 8 + (col >> 1);
                unsigned int* cl = c_lds + (quad * 4) * 36 + c;
                cl[0]      = w0;
                cl[36]     = w1;
                cl[2 * 36] = w2;
                cl[3 * 36] = w3;
            }
        }
        if (t == TT - 1) {
#pragma unroll
            for (int i = 0; i < 4; ++i)
                out[(size_t)(m_base + quad * 4 + i) * HH + n_base + col] =
                    th[i] + (fail ? 1e30f : 0.f);   // poison if protocol broke
        }
        __syncthreads();   // c_lds ready; also fences h_lds/x_lds reuse

        // (7) publish: ONE u64 atomicExch per thread (fire-and-forget),
        //     raw s_barrier (all issued), then flag atomic. No ack RT.
        if (t < TT - 1) {
            const int r  = tid >> 4;          // 0..15
            const int c0 = (tid & 15) * 2;    // 0,2,..,30
            unsigned long long vv =
                (unsigned long long)c_lds[r * 36 + c0] |
                ((unsigned long long)c_lds[r * 36 + c0 + 1] << 32);
            atomicExch((unsigned long long*)
                       (wbu + (size_t)(m * 16 + jj) * 512 + r * 32 + c0), vv);
            __builtin_amdgcn_sched_barrier(0);
            __builtin_amdgcn_s_barrier();     // all data atomics issued
            __builtin_amdgcn_sched_barrier(0);
            if (tid == 0)
                atomicExch((unsigned int*)(flags + (m * 16 + jj) * 32),
                           (unsigned int)(t + 1));
        }
    }
}

extern "C" void kernel_launch(void* const* d_in, const int* in_sizes, int n_in,
                              void* d_out, int out_size, void* d_ws, size_t ws_size,
                              hipStream_t stream) {
    const float* x   = (const float*)d_in[0];
    const float* wih = (const float*)d_in[1];
    const float* whh = (const float*)d_in[2];
    const float* bih = (const float*)d_in[3];
    const float* bhh = (const float*)d_in[4];
    float* out = (float*)d_out;

    unsigned int* hbu0  = (unsigned int*)d_ws;                      // 128 KB
    unsigned int* hbu1  = hbu0 + 32768;                             // 128 KB
    unsigned int* flags = (unsigned int*)((char*)d_ws + 262144);    // 8 KB
    // flag slot: (m*16 + producer) * 32 dwords (128B padding per flag)

    // zero h buffers (h0 = 0, tag bits 0) + flags (ws is poisoned 0xAA)
    hipMemsetAsync(d_ws, 0, 262144 + 8192, stream);

    esn_kernel<<<dim3(64), dim3(256), 0, stream>>>(x, wih, whh, bih, bhh,
                                                   out, hbu0, hbu1, flags);
}